// Round 1
// baseline (673.357 us; speedup 1.0000x reference)
//
#include <hip/hip_runtime.h>
#include <hip/hip_fp16.h>

// Problem constants (fixed by the reference)
#define BB     16
#define CIN    64
#define NN     40962
#define COUT   32
#define NEWN   (4*NN - 6)            // 163842
#define GROUPS_PER_B ((NEWN + 31)/32) // 5121
#define NGROUPS (BB * GROUPS_PER_B)   // 81936

typedef _Float16 f16x8  __attribute__((ext_vector_type(8)));
typedef float    f32x16 __attribute__((ext_vector_type(16)));
typedef _Float16 h2     __attribute__((ext_vector_type(2)));

__device__ __forceinline__ int pk_add_h2(int a, int b) {
  h2 r = __builtin_bit_cast(h2, a) + __builtin_bit_cast(h2, b);
  return __builtin_bit_cast(int, r);
}
__device__ __forceinline__ int pack2(float lo, float hi) {
  h2 r; r.x = (_Float16)lo; r.y = (_Float16)hi;
  return __builtin_bit_cast(int, r);
}

// ---------------- transpose: x (B,64,N) f32  ->  xT (B,N,64) f16 ----------------
// v2: vectorized. float2 global reads (rows are only 8B-aligned: NN%4==2),
// int4 (8x f16) global writes. LDS tile padded to 65 f32 (2-way banks = free).
__global__ __launch_bounds__(256) void k_transpose(const float* __restrict__ x,
                                                   __half* __restrict__ xT) {
  __shared__ float tile[64][65];
  const int b   = blockIdx.y;
  const int n0  = blockIdx.x * 64;
  const int tid = threadIdx.x;
  const float* xb = x + (size_t)b * CIN * NN;

  // ---- read phase: 8 passes x 8 c-rows; thread covers 2 n's via float2 ----
  const int cr8 = tid >> 5;      // 0..7
  const int nh  = tid & 31;      // 0..31 -> n = n0 + nh*2 (+0/1)
  if (n0 + 64 <= NN) {
#pragma unroll
    for (int p = 0; p < 8; ++p) {
      const int c = p * 8 + cr8;
      float2 v = *reinterpret_cast<const float2*>(xb + (size_t)c * NN + n0 + nh * 2);
      tile[c][nh * 2 + 0] = v.x;
      tile[c][nh * 2 + 1] = v.y;
    }
  } else {
#pragma unroll
    for (int p = 0; p < 8; ++p) {
      const int c = p * 8 + cr8;
      const int na = n0 + nh * 2, nb = na + 1;
      tile[c][nh * 2 + 0] = (na < NN) ? xb[(size_t)c * NN + na] : 0.f;
      tile[c][nh * 2 + 1] = (nb < NN) ? xb[(size_t)c * NN + nb] : 0.f;
    }
  }
  __syncthreads();

  // ---- write phase: 2 passes x 32 n-rows; thread writes 8 halfs (int4) ----
  __half* xTb = xT + (size_t)b * NN * CIN;
  const int nr = tid >> 3;   // 0..31
  const int ch = tid & 7;    // 0..7 -> c = ch*8 .. +7
#pragma unroll
  for (int p = 0; p < 2; ++p) {
    const int nl = p * 32 + nr;
    const int n  = n0 + nl;
    if (n < NN) {
      int4 v;
      v.x = pack2(tile[ch * 8 + 0][nl], tile[ch * 8 + 1][nl]);
      v.y = pack2(tile[ch * 8 + 2][nl], tile[ch * 8 + 3][nl]);
      v.z = pack2(tile[ch * 8 + 4][nl], tile[ch * 8 + 5][nl]);
      v.w = pack2(tile[ch * 8 + 6][nl], tile[ch * 8 + 7][nl]);
      *reinterpret_cast<int4*>(xTb + (size_t)n * CIN + ch * 8) = v;
    }
  }
}

// ---------------- MFMA compute: sparse-K=448(+8 bias) GEMM, W register-resident --------
// v2: cross-group software pipeline (double-buffered GD, role-swap to avoid copies),
// int2 load of the down-index pair, nontemporal output stores (keep L2/L3 for xT gathers).
struct GD {
  int4 c0[4], c1[4];   // gathered columns (this k-half)
  int  t0, t1;
  int  b, k;
  bool valid;
};

__device__ __forceinline__ GD load_group(int gid, const __half* __restrict__ xT,
                                         const int* __restrict__ top,
                                         const int* __restrict__ down,
                                         int co, int h) {
  GD d;
  const int b = gid / GROUPS_PER_B;
  const int g = gid - b * GROUPS_PER_B;
  const int k = g * 32 + co;
  d.b = b; d.k = k;
  d.valid = (k < NEWN);
  int j1 = 0, j2 = 0;
  if (d.valid) {
    if (k < NN) { j1 = top[k]; j2 = j1; }
    else {
      int2 jj = *reinterpret_cast<const int2*>(down + 2 * (k - NN));
      j1 = jj.x; j2 = jj.y;
    }
  }
  const int t0 = j1 / NN, n0 = j1 - t0 * NN;
  const int t1 = j2 / NN, n1 = j2 - t1 * NN;
  d.t0 = t0; d.t1 = t1;
  const __half* xTb = xT + (size_t)b * NN * CIN;
  const int4* b0 = (const int4*)(xTb + (size_t)n0 * CIN);
  const int4* b1 = (const int4*)(xTb + (size_t)n1 * CIN);
#pragma unroll
  for (int q = 0; q < 4; ++q) d.c0[q] = b0[2 * q + h];
#pragma unroll
  for (int q = 0; q < 4; ++q) d.c1[q] = b1[2 * q + h];
  return d;
}

__device__ __forceinline__ void compute_store(const GD& d, const int4* __restrict__ Af,
                                              float* __restrict__ out, int h) {
  f32x16 acc;
#pragma unroll
  for (int i = 0; i < 16; ++i) acc[i] = 0.f;
  const int t0 = d.t0, t1 = d.t1;

#pragma unroll
  for (int s = 0; s < 28; ++s) {
    const int t = s >> 2, q = s & 3;
    const bool m0 = (t0 == t), m1 = (t1 == t);
    int4 bb;
    bb.x = pk_add_h2(m0 ? d.c0[q].x : 0, m1 ? d.c1[q].x : 0);
    bb.y = pk_add_h2(m0 ? d.c0[q].y : 0, m1 ? d.c1[q].y : 0);
    bb.z = pk_add_h2(m0 ? d.c0[q].z : 0, m1 ? d.c1[q].z : 0);
    bb.w = pk_add_h2(m0 ? d.c0[q].w : 0, m1 ? d.c1[q].w : 0);
    acc = __builtin_amdgcn_mfma_f32_32x32x16_f16(
        __builtin_bit_cast(f16x8, Af[s]), __builtin_bit_cast(f16x8, bb), acc, 0, 0, 0);
  }

  // bias step: selector chunk on B
  {
    int4 bsel = {0, 0, 0, 0};
    if (h == 0) {
      bsel.x = pack2((float)((t0 == 0) + (t1 == 0)), (float)((t0 == 1) + (t1 == 1)));
      bsel.y = pack2((float)((t0 == 2) + (t1 == 2)), (float)((t0 == 3) + (t1 == 3)));
      bsel.z = pack2((float)((t0 == 4) + (t1 == 4)), (float)((t0 == 5) + (t1 == 5)));
      bsel.w = pack2((float)((t0 == 6) + (t1 == 6)), 0.f);
    }
    acc = __builtin_amdgcn_mfma_f32_32x32x16_f16(
        __builtin_bit_cast(f16x8, Af[28]), __builtin_bit_cast(f16x8, bsel), acc, 0, 0, 0);
  }

  // store: D[co_row][slot], slot = lane&31 -> coalesced 128B segments.
  // Nontemporal: 335MB streaming writes must not evict xT from L2/L3.
  if (d.valid) {
    float* ob = out + (size_t)d.b * COUT * NEWN + d.k;
#pragma unroll
    for (int r = 0; r < 16; ++r) {
      const int corow = (r & 3) + 8 * (r >> 2) + 4 * h;
      __builtin_nontemporal_store(acc[r], ob + (size_t)corow * NEWN);
    }
  }
}

__global__ __launch_bounds__(256, 2) void k_upconv_mfma(
    const __half* __restrict__ xT, const float* __restrict__ W,
    const float* __restrict__ bias, const int* __restrict__ top,
    const int* __restrict__ down, float* __restrict__ out) {
  const int lane = threadIdx.x & 63;
  const int co   = lane & 31;        // A row (M) / output slot (N)
  const int h    = lane >> 5;        // k-half
  const int gwave  = blockIdx.x * (blockDim.x >> 6) + (threadIdx.x >> 6);
  const int nwaves = gridDim.x * (blockDim.x >> 6);

  // ---- Load resident A fragments: 29 steps x 4 dwords = 116 VGPRs ----
  int4 Af[29];
#pragma unroll
  for (int s = 0; s < 28; ++s) {
    const int t  = s >> 2;
    const int c0 = 16 * (s & 3) + 8 * h;
    const float* wr = W + (co * 7 + t) * 64 + c0;
    float4 wa = *(const float4*)wr;
    float4 wb = *(const float4*)(wr + 4);
    Af[s].x = pack2(0.5f * wa.x, 0.5f * wa.y);
    Af[s].y = pack2(0.5f * wa.z, 0.5f * wa.w);
    Af[s].z = pack2(0.5f * wb.x, 0.5f * wb.y);
    Af[s].w = pack2(0.5f * wb.z, 0.5f * wb.w);
  }
  {
    int4 ab = {0, 0, 0, 0};
    if (h == 0) {
      float bv[8];
#pragma unroll
      for (int tau = 0; tau < 7; ++tau) bv[tau] = 0.5f * bias[co * 7 + tau];
      bv[7] = 0.f;
      ab.x = pack2(bv[0], bv[1]);
      ab.y = pack2(bv[2], bv[3]);
      ab.z = pack2(bv[4], bv[5]);
      ab.w = pack2(bv[6], bv[7]);
    }
    Af[28] = ab;
  }

  // ---- software-pipelined grid-stride loop (role-swapped double buffer) ----
  int gid = gwave;                    // gwave < 2048 << NGROUPS: always valid
  GD a = load_group(gid, xT, top, down, co, h);
  for (;;) {
    const int g1 = gid + nwaves;
    const bool h1 = (g1 < NGROUPS);
    GD bN;
    if (h1) bN = load_group(g1, xT, top, down, co, h);  // prefetch overlaps compute(a)
    compute_store(a, Af, out, h);
    if (!h1) return;

    const int g2 = g1 + nwaves;
    const bool h2 = (g2 < NGROUPS);
    if (h2) a = load_group(g2, xT, top, down, co, h);   // prefetch overlaps compute(bN)
    compute_store(bN, Af, out, h);
    if (!h2) return;
    gid = g2;
  }
}

// ---------------- fallback (workspace too small): fp32, strided x reads ----------------
#define WPB 68
#define TPB (32*WPB + 4)

__global__ __launch_bounds__(256) void k_upconv_f32(
    const float* __restrict__ x, const float* __restrict__ W,
    const float* __restrict__ bias, const int* __restrict__ top,
    const int* __restrict__ down, float* __restrict__ out) {
  __shared__ float wl[7 * TPB];
  __shared__ float bl[224];
  const int tid = threadIdx.x;
  for (int p = tid; p < 224 * 64; p += 256) {
    int o = p >> 6, c = p & 63;
    wl[(o % 7) * TPB + (o / 7) * WPB + c] = W[p];
  }
  if (tid < 224) bl[tid] = bias[tid];
  __syncthreads();

  const int b = blockIdx.y;
  const int k = blockIdx.x * 256 + tid;

  int nit = 0, t0 = 0, t1 = 0, n0 = 0, n1 = 0;
  if (k < NEWN) {
    if (k < NN) {
      int j = top[k];
      t0 = j / NN; n0 = j - t0 * NN; nit = 1;
    } else {
      int kk = k - NN;
      int j1 = down[2 * kk], j2 = down[2 * kk + 1];
      t0 = j1 / NN; n0 = j1 - t0 * NN;
      t1 = j2 / NN; n1 = j2 - t1 * NN;
      nit = 2;
    }
  }

  float acc[32];
#pragma unroll
  for (int i = 0; i < 32; ++i) acc[i] = 0.f;

  for (int it = 0; it < nit; ++it) {
    const int t = it ? t1 : t0;
    const int n = it ? n1 : n0;
    const float* col = x + (size_t)b * CIN * NN + n;
    const int base = t * TPB;
#pragma unroll
    for (int ch = 0; ch < 8; ++ch) {
      float xv[8];
#pragma unroll
      for (int q = 0; q < 8; ++q) xv[q] = col[(size_t)(ch * 8 + q) * NN];
#pragma unroll
      for (int co = 0; co < 32; ++co) {
        float a = acc[co];
        const float* wr = &wl[base + co * WPB + ch * 8];
        float4 w0 = *(const float4*)(wr);
        float4 w1 = *(const float4*)(wr + 4);
        a += w0.x * xv[0]; a += w0.y * xv[1]; a += w0.z * xv[2]; a += w0.w * xv[3];
        a += w1.x * xv[4]; a += w1.y * xv[5]; a += w1.z * xv[6]; a += w1.w * xv[7];
        acc[co] = a;
      }
    }
  }

  if (k < NEWN) {
    float* ob = out + (size_t)b * COUT * NEWN + k;
    if (k < NN) {
#pragma unroll
      for (int co = 0; co < 32; ++co)
        ob[(size_t)co * NEWN] = acc[co] + bl[co * 7 + t0];
    } else {
#pragma unroll
      for (int co = 0; co < 32; ++co)
        ob[(size_t)co * NEWN] = 0.5f * (acc[co] + bl[co * 7 + t0] + bl[co * 7 + t1]);
    }
  }
}

extern "C" void kernel_launch(void* const* d_in, const int* in_sizes, int n_in,
                              void* d_out, int out_size, void* d_ws, size_t ws_size,
                              hipStream_t stream) {
  const float* x    = (const float*)d_in[0];
  const float* W    = (const float*)d_in[1];
  const float* bias = (const float*)d_in[2];
  const int*   top  = (const int*)d_in[3];
  const int*   down = (const int*)d_in[4];
  float* out = (float*)d_out;

  const size_t xT_bytes = (size_t)BB * NN * CIN * sizeof(__half);  // ~84 MB
  if (ws_size >= xT_bytes) {
    __half* xT = (__half*)d_ws;
    k_transpose<<<dim3((NN + 63) / 64, BB), 256, 0, stream>>>(x, xT);
    k_upconv_mfma<<<dim3(512), 256, 0, stream>>>(xT, W, bias, top, down, out);
  } else {
    k_upconv_f32<<<dim3((NEWN + 255) / 256, BB), 256, 0, stream>>>(x, W, bias, top, down, out);
  }
}